// Round 1
// baseline (786.635 us; speedup 1.0000x reference)
//
#include <hip/hip_runtime.h>

// Mamba-2 SSD chunked scan, fused single kernel.
// Shapes (hardcoded from setup_inputs):
//   X (8,4096,16,64) f32, initial_states (8,1,16,64,64), A (8,4096,16),
//   B (8,4096,16,64), C (8,4096,16,64), chunk=64.  Output Y (8,4096,16,64) f32.
// Decomposition: block = (b,h,p-half). Sequential over 64 chunks; per chunk:
//   G = C B^T (64x64), M = G * exp(cs_i - cs_j) masked lower-tri,
//   Y = M @ X_half + diag(exp(cs)) C @ state_old^T,
//   state = exp(cs[63]) * state + (X_half^T * diag(exp(cs63-cs))) @ B.

constexpr int Sb  = 8;
constexpr int Ssq = 4096;
constexpr int Hh  = 16;
constexpr int Pp  = 64;
constexpr int Nn  = 64;
constexpr int Ll  = 64;            // chunk length
constexpr int Cc  = Ssq / Ll;      // 64 chunks
constexpr int PH  = 32;            // p-half handled per block

__global__ __launch_bounds__(512)
void ssd_fused_kernel(const float* __restrict__ Xg,
                      const float* __restrict__ Ig,
                      const float* __restrict__ Ag,
                      const float* __restrict__ Bg,
                      const float* __restrict__ Cg,
                      float* __restrict__ Yg)
{
    const int ph  = blockIdx.x;      // 0..1  (p half)
    const int hh  = blockIdx.y;      // 0..15
    const int bb  = blockIdx.z;      // 0..7
    const int tid = threadIdx.x;     // 0..511
    const int p0  = ph * PH;

    __shared__ float sB[Ll][Nn + 4];     // stride 68
    __shared__ float sC[Ll][Nn + 4];
    __shared__ float sG[Ll][Ll + 4];
    __shared__ float sX[Ll][PH + 4];     // stride 36
    __shared__ float sSt[PH][Nn + 4];    // running state (p-half x n)
    __shared__ float scs[Ll];            // cumsum(A)
    __shared__ float sdo[Ll];            // exp(cs)
    __shared__ float sdi[Ll];            // exp(-cs)
    __shared__ float sds[Ll];            // exp(cs[63]-cs)

    // ---- load initial state (b,1,h,p,n) ----
    {
        const int r = tid >> 4;              // 0..31
        const int c = (tid & 15) * 4;        // 0..60
        const size_t off = (((size_t)bb * Hh + hh) * Pp + (p0 + r)) * (size_t)Nn + c;
        const float4 v = *reinterpret_cast<const float4*>(&Ig[off]);
        sSt[r][c + 0] = v.x; sSt[r][c + 1] = v.y;
        sSt[r][c + 2] = v.z; sSt[r][c + 3] = v.w;
    }

    for (int ch = 0; ch < Cc; ++ch) {
        __syncthreads();   // previous chunk's readers done (and init-state load)
        const size_t tbase = (size_t)bb * Ssq + (size_t)ch * Ll;

        // ---- stage B, C (64x64 each) ----
        #pragma unroll
        for (int q = tid; q < 1024; q += 512) {
            const int r = q >> 4;
            const int c = (q & 15) * 4;
            const size_t off = ((tbase + r) * Hh + hh) * (size_t)Nn + c;
            const float4 vb = *reinterpret_cast<const float4*>(&Bg[off]);
            sB[r][c + 0] = vb.x; sB[r][c + 1] = vb.y;
            sB[r][c + 2] = vb.z; sB[r][c + 3] = vb.w;
            const float4 vc = *reinterpret_cast<const float4*>(&Cg[off]);
            sC[r][c + 0] = vc.x; sC[r][c + 1] = vc.y;
            sC[r][c + 2] = vc.z; sC[r][c + 3] = vc.w;
        }
        // ---- stage X half (64x32) ----
        {
            const int r = tid >> 3;
            const int c = (tid & 7) * 4;
            const size_t off = ((tbase + r) * Hh + hh) * (size_t)Pp + p0 + c;
            const float4 v = *reinterpret_cast<const float4*>(&Xg[off]);
            sX[r][c + 0] = v.x; sX[r][c + 1] = v.y;
            sX[r][c + 2] = v.z; sX[r][c + 3] = v.w;
        }
        // ---- A: wave-64 inclusive scan + decay tables ----
        if (tid < 64) {
            float v = Ag[(tbase + tid) * Hh + hh];
            #pragma unroll
            for (int o = 1; o < 64; o <<= 1) {
                const float u = __shfl_up(v, o, 64);
                if (tid >= o) v += u;
            }
            scs[tid] = v;
            const float last = __shfl(v, 63, 64);
            sdo[tid] = expf(v);
            sdi[tid] = expf(-v);
            sds[tid] = expf(last - v);
        }
        __syncthreads();

        // ---- G = C B^T, then M = G * exp(cs_i-cs_j) masked ----
        {
            const int i0 = (tid >> 4) * 2;   // 0..62
            const int j0 = (tid & 15) * 4;   // 0..60
            float a00 = 0, a01 = 0, a02 = 0, a03 = 0;
            float a10 = 0, a11 = 0, a12 = 0, a13 = 0;
            #pragma unroll
            for (int k = 0; k < 64; k += 4) {
                const float4 c0 = *reinterpret_cast<const float4*>(&sC[i0][k]);
                const float4 c1 = *reinterpret_cast<const float4*>(&sC[i0 + 1][k]);
                const float4 b0 = *reinterpret_cast<const float4*>(&sB[j0][k]);
                const float4 b1 = *reinterpret_cast<const float4*>(&sB[j0 + 1][k]);
                const float4 b2 = *reinterpret_cast<const float4*>(&sB[j0 + 2][k]);
                const float4 b3 = *reinterpret_cast<const float4*>(&sB[j0 + 3][k]);
                a00 += c0.x*b0.x + c0.y*b0.y + c0.z*b0.z + c0.w*b0.w;
                a01 += c0.x*b1.x + c0.y*b1.y + c0.z*b1.z + c0.w*b1.w;
                a02 += c0.x*b2.x + c0.y*b2.y + c0.z*b2.z + c0.w*b2.w;
                a03 += c0.x*b3.x + c0.y*b3.y + c0.z*b3.z + c0.w*b3.w;
                a10 += c1.x*b0.x + c1.y*b0.y + c1.z*b0.z + c1.w*b0.w;
                a11 += c1.x*b1.x + c1.y*b1.y + c1.z*b1.z + c1.w*b1.w;
                a12 += c1.x*b2.x + c1.y*b2.y + c1.z*b2.z + c1.w*b2.w;
                a13 += c1.x*b3.x + c1.y*b3.y + c1.z*b3.z + c1.w*b3.w;
            }
            const float ei0 = sdo[i0], ei1 = sdo[i0 + 1];
            const float d0 = sdi[j0 + 0], d1 = sdi[j0 + 1];
            const float d2 = sdi[j0 + 2], d3 = sdi[j0 + 3];
            sG[i0][j0 + 0]     = (i0     >= j0 + 0) ? a00 * ei0 * d0 : 0.0f;
            sG[i0][j0 + 1]     = (i0     >= j0 + 1) ? a01 * ei0 * d1 : 0.0f;
            sG[i0][j0 + 2]     = (i0     >= j0 + 2) ? a02 * ei0 * d2 : 0.0f;
            sG[i0][j0 + 3]     = (i0     >= j0 + 3) ? a03 * ei0 * d3 : 0.0f;
            sG[i0 + 1][j0 + 0] = (i0 + 1 >= j0 + 0) ? a10 * ei1 * d0 : 0.0f;
            sG[i0 + 1][j0 + 1] = (i0 + 1 >= j0 + 1) ? a11 * ei1 * d1 : 0.0f;
            sG[i0 + 1][j0 + 2] = (i0 + 1 >= j0 + 2) ? a12 * ei1 * d2 : 0.0f;
            sG[i0 + 1][j0 + 3] = (i0 + 1 >= j0 + 3) ? a13 * ei1 * d3 : 0.0f;
        }
        __syncthreads();

        // ---- Y = M @ X + diag(exp(cs)) * (C @ state_old^T) ----
        {
            const int l0 = (tid >> 4) * 2;   // row pair
            const int q0 = (tid & 15) * 2;   // local p col pair
            float y00 = 0, y01 = 0, y10 = 0, y11 = 0;
            #pragma unroll
            for (int s = 0; s < 64; s += 4) {
                const float4 g0 = *reinterpret_cast<const float4*>(&sG[l0][s]);
                const float4 g1 = *reinterpret_cast<const float4*>(&sG[l0 + 1][s]);
                const float x00 = sX[s][q0],     x01 = sX[s][q0 + 1];
                const float x10 = sX[s + 1][q0], x11 = sX[s + 1][q0 + 1];
                const float x20 = sX[s + 2][q0], x21 = sX[s + 2][q0 + 1];
                const float x30 = sX[s + 3][q0], x31 = sX[s + 3][q0 + 1];
                y00 += g0.x*x00 + g0.y*x10 + g0.z*x20 + g0.w*x30;
                y01 += g0.x*x01 + g0.y*x11 + g0.z*x21 + g0.w*x31;
                y10 += g1.x*x00 + g1.y*x10 + g1.z*x20 + g1.w*x30;
                y11 += g1.x*x01 + g1.y*x11 + g1.z*x21 + g1.w*x31;
            }
            float o00 = 0, o01 = 0, o10 = 0, o11 = 0;
            #pragma unroll
            for (int n = 0; n < 64; n += 4) {
                const float4 c0 = *reinterpret_cast<const float4*>(&sC[l0][n]);
                const float4 c1 = *reinterpret_cast<const float4*>(&sC[l0 + 1][n]);
                const float4 s0 = *reinterpret_cast<const float4*>(&sSt[q0][n]);
                const float4 s1 = *reinterpret_cast<const float4*>(&sSt[q0 + 1][n]);
                o00 += c0.x*s0.x + c0.y*s0.y + c0.z*s0.z + c0.w*s0.w;
                o01 += c0.x*s1.x + c0.y*s1.y + c0.z*s1.z + c0.w*s1.w;
                o10 += c1.x*s0.x + c1.y*s0.y + c1.z*s0.z + c1.w*s0.w;
                o11 += c1.x*s1.x + c1.y*s1.y + c1.z*s1.z + c1.w*s1.w;
            }
            const float e0 = sdo[l0], e1 = sdo[l0 + 1];
            y00 += e0 * o00; y01 += e0 * o01;
            y10 += e1 * o10; y11 += e1 * o11;
            const size_t yb0 = ((tbase + l0) * Hh + hh) * (size_t)Pp + p0 + q0;
            const size_t yb1 = ((tbase + l0 + 1) * Hh + hh) * (size_t)Pp + p0 + q0;
            Yg[yb0] = y00; Yg[yb0 + 1] = y01;
            Yg[yb1] = y10; Yg[yb1 + 1] = y11;
        }
        __syncthreads();

        // ---- state = exp(cs63)*state + (X^T * diag(exp(cs63-cs))) @ B ----
        {
            const int r0 = (tid >> 5) * 2;     // p rows (0..30)
            const int n0 = (tid & 31) * 2;     // n cols (0..62)
            float a00 = 0, a01 = 0, a10 = 0, a11 = 0;
            #pragma unroll 4
            for (int l = 0; l < 64; ++l) {
                const float d  = sds[l];
                const float x0 = sX[l][r0] * d;
                const float x1 = sX[l][r0 + 1] * d;
                const float b0 = sB[l][n0];
                const float b1 = sB[l][n0 + 1];
                a00 += x0 * b0; a01 += x0 * b1;
                a10 += x1 * b0; a11 += x1 * b1;
            }
            const float dA = sdo[63];   // exp(cs[63])
            sSt[r0][n0]         = dA * sSt[r0][n0]         + a00;
            sSt[r0][n0 + 1]     = dA * sSt[r0][n0 + 1]     + a01;
            sSt[r0 + 1][n0]     = dA * sSt[r0 + 1][n0]     + a10;
            sSt[r0 + 1][n0 + 1] = dA * sSt[r0 + 1][n0 + 1] + a11;
        }
    }
}

extern "C" void kernel_launch(void* const* d_in, const int* in_sizes, int n_in,
                              void* d_out, int out_size, void* d_ws, size_t ws_size,
                              hipStream_t stream) {
    const float* X  = (const float*)d_in[0];
    const float* I  = (const float*)d_in[1];
    const float* A  = (const float*)d_in[2];
    const float* Bp = (const float*)d_in[3];
    const float* Cp = (const float*)d_in[4];
    float* Y = (float*)d_out;
    dim3 grid(2, Hh, Sb);
    ssd_fused_kernel<<<grid, 512, 0, stream>>>(X, I, A, Bp, Cp, Y);
}

// Round 2
// 226.090 us; speedup vs baseline: 3.4793x; 3.4793x over previous
//
#include <hip/hip_runtime.h>

// Mamba-2 SSD chunked scan, 3-phase MFMA decomposition.
// Shapes: X (8,4096,16,64) f32, init (8,1,16,64,64), A (8,4096,16),
//         B/C (8,4096,16,64), chunk=64. Output Y (8,4096,16,64) f32.
// Phase A: per (b,h,c): chunk_state[p][n] = sum_l X[l][p]*exp(cs63-cs_l)*B[l][n]  (MFMA)
// Phase B: per (b,h): in-place prefix scan: prefix[c] = running; running = e^{cs63[c]}*running + chunk[c]
// Phase C: per (b,h,c): G=C B^T -> M = G*e^{cs_i-cs_j} masked; Y = M@X + diag(e^{cs})*(C@prefix^T)

typedef __bf16 bf16x4 __attribute__((ext_vector_type(4)));
typedef __bf16 bf16x8 __attribute__((ext_vector_type(8)));
typedef float  f32x4  __attribute__((ext_vector_type(4)));

constexpr int LDT = 72;   // padded LDS row stride (bf16 elems), 144 B = 16B-multiple

__device__ __forceinline__ f32x4 mfma16(bf16x8 a, bf16x8 b, f32x4 c) {
    return __builtin_amdgcn_mfma_f32_16x16x32_bf16(a, b, c, 0, 0, 0);
}

// ---------------- Phase A: chunk states ----------------
__global__ __launch_bounds__(256)
void kA_chunkstate(const float* __restrict__ Xg, const float* __restrict__ Ag,
                   const float* __restrict__ Bg, __bf16* __restrict__ states,
                   float* __restrict__ cs63)
{
    const int cc = blockIdx.x, hh = blockIdx.y, bb = blockIdx.z;
    const int tid = threadIdx.x;
    __shared__ __bf16 sXt[64][LDT];   // X^T scaled: [p][l]
    __shared__ __bf16 sBt[64][LDT];   // B^T:        [n][l]
    __shared__ float  sds[64];
    const size_t tbase = (size_t)bb*4096 + cc*64;

    if (tid < 64) {
        float v = Ag[(tbase + tid)*16 + hh];
        #pragma unroll
        for (int o = 1; o < 64; o <<= 1) { float u = __shfl_up(v, o, 64); if (tid >= o) v += u; }
        const float last = __shfl(v, 63, 64);
        sds[tid] = expf(last - v);
        if (tid == 63) cs63[((size_t)bb*16 + hh)*64 + cc] = v;
    }
    __syncthreads();

    #pragma unroll
    for (int it = 0; it < 4; ++it) {
        const int flat = tid + 256*it;          // 0..1023
        const int l  = flat >> 4;               // seq row
        const int c4 = (flat & 15) * 4;         // p / n column group
        const float d = sds[l];
        const size_t gofs = ((tbase + l)*16 + hh)*(size_t)64 + c4;
        const float4 xv = *reinterpret_cast<const float4*>(&Xg[gofs]);
        sXt[c4+0][l] = (__bf16)(xv.x*d);
        sXt[c4+1][l] = (__bf16)(xv.y*d);
        sXt[c4+2][l] = (__bf16)(xv.z*d);
        sXt[c4+3][l] = (__bf16)(xv.w*d);
        const float4 bv = *reinterpret_cast<const float4*>(&Bg[gofs]);
        sBt[c4+0][l] = (__bf16)bv.x;
        sBt[c4+1][l] = (__bf16)bv.y;
        sBt[c4+2][l] = (__bf16)bv.z;
        sBt[c4+3][l] = (__bf16)bv.w;
    }
    __syncthreads();

    const int lane = tid & 63;
    const int wm = ((tid >> 7) & 1) * 32;   // p-quadrant
    const int wn = ((tid >> 6) & 1) * 32;   // n-quadrant
    const int fr = lane & 15, fg = lane >> 4;

    f32x4 acc[2][2] = {};
    #pragma unroll
    for (int ks = 0; ks < 2; ++ks) {
        const int k0 = ks*32 + fg*8;
        const bf16x8 a0 = *reinterpret_cast<const bf16x8*>(&sXt[wm      + fr][k0]);
        const bf16x8 a1 = *reinterpret_cast<const bf16x8*>(&sXt[wm + 16 + fr][k0]);
        const bf16x8 b0 = *reinterpret_cast<const bf16x8*>(&sBt[wn      + fr][k0]);
        const bf16x8 b1 = *reinterpret_cast<const bf16x8*>(&sBt[wn + 16 + fr][k0]);
        acc[0][0] = mfma16(a0, b0, acc[0][0]);
        acc[0][1] = mfma16(a0, b1, acc[0][1]);
        acc[1][0] = mfma16(a1, b0, acc[1][0]);
        acc[1][1] = mfma16(a1, b1, acc[1][1]);
    }
    __syncthreads();            // done reading sXt; reuse as output staging

    __bf16 (*sOut)[LDT] = sXt;  // [p][n]
    #pragma unroll
    for (int mt = 0; mt < 2; ++mt)
        #pragma unroll
        for (int nt = 0; nt < 2; ++nt)
            #pragma unroll
            for (int r = 0; r < 4; ++r)
                sOut[wm + 16*mt + fg*4 + r][wn + 16*nt + fr] = (__bf16)acc[mt][nt][r];
    __syncthreads();

    __bf16* dst = states + (((size_t)bb*16 + hh)*64 + cc)*(size_t)4096;
    #pragma unroll
    for (int it = 0; it < 2; ++it) {
        const int flat = tid + 256*it;      // 0..511
        const int p = flat >> 3, n8 = (flat & 7)*8;
        *reinterpret_cast<bf16x8*>(&dst[p*64 + n8]) =
            *reinterpret_cast<const bf16x8*>(&sOut[p][n8]);
    }
}

// ---------------- Phase B: prefix scan over chunks (in-place) ----------------
__global__ __launch_bounds__(256)
void kB_scan(const float* __restrict__ Ig, __bf16* __restrict__ states,
             const float* __restrict__ cs63)
{
    const int ph = blockIdx.x, hh = blockIdx.y, bb = blockIdx.z;
    const int tid = threadIdx.x;
    const int p  = ph*32 + (tid >> 3);
    const int n8 = (tid & 7) * 8;
    const float* ip = &Ig[(((size_t)bb*16 + hh)*64 + p)*(size_t)64 + n8];
    const float4 i0 = *reinterpret_cast<const float4*>(ip);
    const float4 i1 = *reinterpret_cast<const float4*>(ip + 4);
    float r[8] = {i0.x, i0.y, i0.z, i0.w, i1.x, i1.y, i1.z, i1.w};
    const float* csp = &cs63[((size_t)bb*16 + hh)*64];
    __bf16* sp = states + ((size_t)bb*16 + hh)*64*4096 + p*64 + n8;

    for (int c = 0; c < 64; ++c) {
        const float d = expf(csp[c]);
        const bf16x8 sv = *reinterpret_cast<const bf16x8*>(sp + (size_t)c*4096);
        bf16x8 pr;
        #pragma unroll
        for (int j = 0; j < 8; ++j) pr[j] = (__bf16)r[j];
        *reinterpret_cast<bf16x8*>(sp + (size_t)c*4096) = pr;   // prefix[c]
        #pragma unroll
        for (int j = 0; j < 8; ++j) r[j] = fmaf(d, r[j], (float)sv[j]);
    }
}

// ---------------- Phase C: outputs ----------------
struct SMemC {
    __bf16 Ct[64][LDT];   // C row-major [l][n]
    __bf16 Bm[64][LDT];   // B row-major [l][n]
    __bf16 Xt[64][LDT];   // X^T [p][l]
    __bf16 Sp[64][LDT];   // prefix state [p][n]
    __bf16 M [64][LDT];   // masked decay matrix [i][j]
    float  dout[64];
    float  din[64];
};

__global__ __launch_bounds__(256)
void kC_output(const float* __restrict__ Xg, const float* __restrict__ Ag,
               const float* __restrict__ Bg, const float* __restrict__ Cg,
               const __bf16* __restrict__ states, float* __restrict__ Yg)
{
    const int cc = blockIdx.x, hh = blockIdx.y, bb = blockIdx.z;
    const int tid = threadIdx.x;
    __shared__ __align__(16) SMemC sm;
    const size_t tbase = (size_t)bb*4096 + cc*64;

    if (tid < 64) {
        float v = Ag[(tbase + tid)*16 + hh];
        #pragma unroll
        for (int o = 1; o < 64; o <<= 1) { float u = __shfl_up(v, o, 64); if (tid >= o) v += u; }
        sm.dout[tid] = expf(v);
        sm.din[tid]  = expf(-v);
    }

    #pragma unroll
    for (int it = 0; it < 4; ++it) {
        const int flat = tid + 256*it;
        const int l  = flat >> 4;
        const int c4 = (flat & 15)*4;
        const size_t gofs = ((tbase + l)*16 + hh)*(size_t)64 + c4;
        const float4 cv = *reinterpret_cast<const float4*>(&Cg[gofs]);
        *reinterpret_cast<bf16x4*>(&sm.Ct[l][c4]) =
            (bf16x4){(__bf16)cv.x, (__bf16)cv.y, (__bf16)cv.z, (__bf16)cv.w};
        const float4 bv = *reinterpret_cast<const float4*>(&Bg[gofs]);
        *reinterpret_cast<bf16x4*>(&sm.Bm[l][c4]) =
            (bf16x4){(__bf16)bv.x, (__bf16)bv.y, (__bf16)bv.z, (__bf16)bv.w};
        const float4 xv = *reinterpret_cast<const float4*>(&Xg[gofs]);
        sm.Xt[c4+0][l] = (__bf16)xv.x;
        sm.Xt[c4+1][l] = (__bf16)xv.y;
        sm.Xt[c4+2][l] = (__bf16)xv.z;
        sm.Xt[c4+3][l] = (__bf16)xv.w;
    }
    {
        const __bf16* st = states + (((size_t)bb*16 + hh)*64 + cc)*(size_t)4096;
        #pragma unroll
        for (int it = 0; it < 2; ++it) {
            const int flat = tid + 256*it;
            const int p = flat >> 3, n8 = (flat & 7)*8;
            *reinterpret_cast<bf16x8*>(&sm.Sp[p][n8]) =
                *reinterpret_cast<const bf16x8*>(&st[p*64 + n8]);
        }
    }
    __syncthreads();

    const int lane = tid & 63;
    const int wm = ((tid >> 7) & 1) * 32;
    const int wn = ((tid >> 6) & 1) * 32;
    const int fr = lane & 15, fg = lane >> 4;

    // ---- G = C B^T -> M ----
    {
        f32x4 g[2][2] = {};
        #pragma unroll
        for (int ks = 0; ks < 2; ++ks) {
            const int k0 = ks*32 + fg*8;
            const bf16x8 a0 = *reinterpret_cast<const bf16x8*>(&sm.Ct[wm      + fr][k0]);
            const bf16x8 a1 = *reinterpret_cast<const bf16x8*>(&sm.Ct[wm + 16 + fr][k0]);
            const bf16x8 b0 = *reinterpret_cast<const bf16x8*>(&sm.Bm[wn      + fr][k0]);
            const bf16x8 b1 = *reinterpret_cast<const bf16x8*>(&sm.Bm[wn + 16 + fr][k0]);
            g[0][0] = mfma16(a0, b0, g[0][0]);
            g[0][1] = mfma16(a0, b1, g[0][1]);
            g[1][0] = mfma16(a1, b0, g[1][0]);
            g[1][1] = mfma16(a1, b1, g[1][1]);
        }
        #pragma unroll
        for (int mt = 0; mt < 2; ++mt)
            #pragma unroll
            for (int nt = 0; nt < 2; ++nt) {
                const int j = wn + 16*nt + fr;
                const float dj = sm.din[j];
                #pragma unroll
                for (int r = 0; r < 4; ++r) {
                    const int i = wm + 16*mt + fg*4 + r;
                    const float val = (i >= j) ? g[mt][nt][r] * sm.dout[i] * dj : 0.0f;
                    sm.M[i][j] = (__bf16)val;
                }
            }
    }
    __syncthreads();

    // ---- Y = M @ X + diag(dout) * (C @ Sp^T) ----
    f32x4 ad[2][2] = {}, ao[2][2] = {};
    #pragma unroll
    for (int ks = 0; ks < 2; ++ks) {
        const int k0 = ks*32 + fg*8;
        const bf16x8 m0 = *reinterpret_cast<const bf16x8*>(&sm.M [wm      + fr][k0]);
        const bf16x8 m1 = *reinterpret_cast<const bf16x8*>(&sm.M [wm + 16 + fr][k0]);
        const bf16x8 x0 = *reinterpret_cast<const bf16x8*>(&sm.Xt[wn      + fr][k0]);
        const bf16x8 x1 = *reinterpret_cast<const bf16x8*>(&sm.Xt[wn + 16 + fr][k0]);
        ad[0][0] = mfma16(m0, x0, ad[0][0]);
        ad[0][1] = mfma16(m0, x1, ad[0][1]);
        ad[1][0] = mfma16(m1, x0, ad[1][0]);
        ad[1][1] = mfma16(m1, x1, ad[1][1]);
        const bf16x8 c0 = *reinterpret_cast<const bf16x8*>(&sm.Ct[wm      + fr][k0]);
        const bf16x8 c1 = *reinterpret_cast<const bf16x8*>(&sm.Ct[wm + 16 + fr][k0]);
        const bf16x8 s0 = *reinterpret_cast<const bf16x8*>(&sm.Sp[wn      + fr][k0]);
        const bf16x8 s1 = *reinterpret_cast<const bf16x8*>(&sm.Sp[wn + 16 + fr][k0]);
        ao[0][0] = mfma16(c0, s0, ao[0][0]);
        ao[0][1] = mfma16(c0, s1, ao[0][1]);
        ao[1][0] = mfma16(c1, s0, ao[1][0]);
        ao[1][1] = mfma16(c1, s1, ao[1][1]);
    }
    __syncthreads();   // all LDS reads done; reuse front of sm for Y staging

    float (*sY)[68] = reinterpret_cast<float(*)[68]>(&sm);   // 64x68 f32 = 17408 B (< Ct+Bm)
    #pragma unroll
    for (int mt = 0; mt < 2; ++mt)
        #pragma unroll
        for (int nt = 0; nt < 2; ++nt) {
            const int pcol = wn + 16*nt + fr;
            #pragma unroll
            for (int r = 0; r < 4; ++r) {
                const int i = wm + 16*mt + fg*4 + r;
                sY[i][pcol] = ad[mt][nt][r] + sm.dout[i]*ao[mt][nt][r];
            }
        }
    __syncthreads();

    #pragma unroll
    for (int it = 0; it < 4; ++it) {
        const int flat = tid + 256*it;        // 0..1023 float4s
        const int row = flat >> 4;
        const int q4  = (flat & 15)*4;
        const float4 v = *reinterpret_cast<const float4*>(&sY[row][q4]);
        *reinterpret_cast<float4*>(&Yg[((tbase + row)*16 + hh)*(size_t)64 + q4]) = v;
    }
}

extern "C" void kernel_launch(void* const* d_in, const int* in_sizes, int n_in,
                              void* d_out, int out_size, void* d_ws, size_t ws_size,
                              hipStream_t stream) {
    const float* X  = (const float*)d_in[0];
    const float* I  = (const float*)d_in[1];
    const float* A  = (const float*)d_in[2];
    const float* Bp = (const float*)d_in[3];
    const float* Cp = (const float*)d_in[4];
    float* Y = (float*)d_out;
    __bf16* states = (__bf16*)d_ws;                                   // 67,108,864 B
    float*  cs63   = (float*)((char*)d_ws + (size_t)67108864);        // 32,768 B

    kA_chunkstate<<<dim3(64,16,8), 256, 0, stream>>>(X, A, Bp, states, cs63);
    kB_scan      <<<dim3(2,16,8),  256, 0, stream>>>(I, states, cs63);
    kC_output    <<<dim3(64,16,8), 256, 0, stream>>>(X, A, Bp, Cp, states, Y);
}

// Round 3
// 217.634 us; speedup vs baseline: 3.6145x; 1.0389x over previous
//
#include <hip/hip_runtime.h>

// Mamba-2 SSD chunked scan, 3-phase MFMA decomposition (round 3).
// Phase A: chunk_state[p][n] = sum_l X[l][p]*exp(cs63-cs_l)*B[l][n]  (MFMA)
// Phase B: prefix scan over chunks (in-place, prefetched)
// Phase C: G=C B^T -> M masked decay; Y = M@X + diag(e^{cs})*(C@prefix^T)
// Round-3 changes: loads issued before A-scan; kC LDS 46.6->37.4 KB via
// M-over-B and Y-over-(Ct,Sp) overlays (4 blocks/CU); merged MFMA phase 1;
// kB prefetch. launch_bounds(256,4) caps VGPR at 128 to hold occupancy.

typedef __bf16 bf16x4 __attribute__((ext_vector_type(4)));
typedef __bf16 bf16x8 __attribute__((ext_vector_type(8)));
typedef float  f32x4  __attribute__((ext_vector_type(4)));

constexpr int LDT = 72;   // padded LDS row stride (bf16), 144 B = 16B-multiple

__device__ __forceinline__ f32x4 mfma16(bf16x8 a, bf16x8 b, f32x4 c) {
    return __builtin_amdgcn_mfma_f32_16x16x32_bf16(a, b, c, 0, 0, 0);
}

// ---------------- Phase A: chunk states ----------------
__global__ __launch_bounds__(256, 4)
void kA_chunkstate(const float* __restrict__ Xg, const float* __restrict__ Ag,
                   const float* __restrict__ Bg, __bf16* __restrict__ states,
                   float* __restrict__ cs63)
{
    const int cc = blockIdx.x, hh = blockIdx.y, bb = blockIdx.z;
    const int tid = threadIdx.x;
    __shared__ __bf16 sXt[64][LDT];   // X^T scaled: [p][l]
    __shared__ __bf16 sBt[64][LDT];   // B^T:        [n][l]
    __shared__ float  sds[64];
    const size_t tbase = (size_t)bb*4096 + cc*64;

    // ---- issue all global loads first (latency hidden under scan) ----
    float4 xv[4], bv[4];
    #pragma unroll
    for (int it = 0; it < 4; ++it) {
        const int flat = tid + 256*it;
        const int l  = flat >> 4;
        const int c4 = (flat & 15) * 4;
        const size_t gofs = ((tbase + l)*16 + hh)*(size_t)64 + c4;
        xv[it] = *reinterpret_cast<const float4*>(&Xg[gofs]);
        bv[it] = *reinterpret_cast<const float4*>(&Bg[gofs]);
    }
    // ---- A scan (wave 0) ----
    if (tid < 64) {
        float v = Ag[(tbase + tid)*16 + hh];
        #pragma unroll
        for (int o = 1; o < 64; o <<= 1) { float u = __shfl_up(v, o, 64); if (tid >= o) v += u; }
        const float last = __shfl(v, 63, 64);
        sds[tid] = expf(last - v);
        if (tid == 63) cs63[((size_t)bb*16 + hh)*64 + cc] = v;
    }
    // B^T staging does not need the scan result
    #pragma unroll
    for (int it = 0; it < 4; ++it) {
        const int flat = tid + 256*it;
        const int l  = flat >> 4;
        const int c4 = (flat & 15) * 4;
        sBt[c4+0][l] = (__bf16)bv[it].x;
        sBt[c4+1][l] = (__bf16)bv[it].y;
        sBt[c4+2][l] = (__bf16)bv[it].z;
        sBt[c4+3][l] = (__bf16)bv[it].w;
    }
    __syncthreads();   // sds ready
    #pragma unroll
    for (int it = 0; it < 4; ++it) {
        const int flat = tid + 256*it;
        const int l  = flat >> 4;
        const int c4 = (flat & 15) * 4;
        const float d = sds[l];
        sXt[c4+0][l] = (__bf16)(xv[it].x*d);
        sXt[c4+1][l] = (__bf16)(xv[it].y*d);
        sXt[c4+2][l] = (__bf16)(xv[it].z*d);
        sXt[c4+3][l] = (__bf16)(xv[it].w*d);
    }
    __syncthreads();

    const int lane = tid & 63;
    const int wm = ((tid >> 7) & 1) * 32;   // p-quadrant
    const int wn = ((tid >> 6) & 1) * 32;   // n-quadrant
    const int fr = lane & 15, fg = lane >> 4;

    f32x4 acc[2][2] = {};
    #pragma unroll
    for (int ks = 0; ks < 2; ++ks) {
        const int k0 = ks*32 + fg*8;
        const bf16x8 a0 = *reinterpret_cast<const bf16x8*>(&sXt[wm      + fr][k0]);
        const bf16x8 a1 = *reinterpret_cast<const bf16x8*>(&sXt[wm + 16 + fr][k0]);
        const bf16x8 b0 = *reinterpret_cast<const bf16x8*>(&sBt[wn      + fr][k0]);
        const bf16x8 b1 = *reinterpret_cast<const bf16x8*>(&sBt[wn + 16 + fr][k0]);
        acc[0][0] = mfma16(a0, b0, acc[0][0]);
        acc[0][1] = mfma16(a0, b1, acc[0][1]);
        acc[1][0] = mfma16(a1, b0, acc[1][0]);
        acc[1][1] = mfma16(a1, b1, acc[1][1]);
    }
    __syncthreads();            // done reading sXt; reuse as output staging

    __bf16 (*sOut)[LDT] = sXt;  // [p][n]
    #pragma unroll
    for (int mt = 0; mt < 2; ++mt)
        #pragma unroll
        for (int nt = 0; nt < 2; ++nt)
            #pragma unroll
            for (int r = 0; r < 4; ++r)
                sOut[wm + 16*mt + fg*4 + r][wn + 16*nt + fr] = (__bf16)acc[mt][nt][r];
    __syncthreads();

    __bf16* dst = states + (((size_t)bb*16 + hh)*64 + cc)*(size_t)4096;
    #pragma unroll
    for (int it = 0; it < 2; ++it) {
        const int flat = tid + 256*it;      // 0..511
        const int p = flat >> 3, n8 = (flat & 7)*8;
        *reinterpret_cast<bf16x8*>(&dst[p*64 + n8]) =
            *reinterpret_cast<const bf16x8*>(&sOut[p][n8]);
    }
}

// ---------------- Phase B: prefix scan over chunks (in-place) ----------------
__global__ __launch_bounds__(256)
void kB_scan(const float* __restrict__ Ig, __bf16* __restrict__ states,
             const float* __restrict__ cs63)
{
    const int ph = blockIdx.x, hh = blockIdx.y, bb = blockIdx.z;
    const int tid = threadIdx.x;
    const int p  = ph*32 + (tid >> 3);
    const int n8 = (tid & 7) * 8;
    const float* ip = &Ig[(((size_t)bb*16 + hh)*64 + p)*(size_t)64 + n8];
    const float4 i0 = *reinterpret_cast<const float4*>(ip);
    const float4 i1 = *reinterpret_cast<const float4*>(ip + 4);
    float r[8] = {i0.x, i0.y, i0.z, i0.w, i1.x, i1.y, i1.z, i1.w};
    const float* csp = &cs63[((size_t)bb*16 + hh)*64];
    __bf16* sp = states + ((size_t)bb*16 + hh)*64*4096 + p*64 + n8;

    bf16x8 nxt = *reinterpret_cast<const bf16x8*>(sp);
    float dnxt = expf(csp[0]);
    for (int c = 0; c < 64; ++c) {
        const bf16x8 cur = nxt;
        const float d = dnxt;
        if (c < 63) {
            nxt = *reinterpret_cast<const bf16x8*>(sp + (size_t)(c + 1)*4096);
            dnxt = expf(csp[c + 1]);
        }
        bf16x8 pr;
        #pragma unroll
        for (int j = 0; j < 8; ++j) pr[j] = (__bf16)r[j];
        *reinterpret_cast<bf16x8*>(sp + (size_t)c*4096) = pr;   // prefix[c]
        #pragma unroll
        for (int j = 0; j < 8; ++j) r[j] = fmaf(d, r[j], (float)cur[j]);
    }
}

// ---------------- Phase C: outputs ----------------
struct SMemC {
    __bf16 Ct[64][LDT];   // C row-major [l][n]   (later: Y staging, with Sp)
    __bf16 Sp[64][LDT];   // prefix state [p][n]
    __bf16 BM[64][LDT];   // B row-major [l][n], then overlaid by M [i][j]
    __bf16 Xt[64][LDT];   // X^T [p][l]
    float  dout[64];
    float  din[64];
};

__global__ __launch_bounds__(256, 4)
void kC_output(const float* __restrict__ Xg, const float* __restrict__ Ag,
               const float* __restrict__ Bg, const float* __restrict__ Cg,
               const __bf16* __restrict__ states, float* __restrict__ Yg)
{
    const int cc = blockIdx.x, hh = blockIdx.y, bb = blockIdx.z;
    const int tid = threadIdx.x;
    __shared__ __align__(16) SMemC sm;
    const size_t tbase = (size_t)bb*4096 + cc*64;

    // ---- issue all global loads first ----
    float4 cv[4], bv[4], xv[4];
    #pragma unroll
    for (int it = 0; it < 4; ++it) {
        const int flat = tid + 256*it;
        const int l  = flat >> 4;
        const int c4 = (flat & 15)*4;
        const size_t gofs = ((tbase + l)*16 + hh)*(size_t)64 + c4;
        cv[it] = *reinterpret_cast<const float4*>(&Cg[gofs]);
        bv[it] = *reinterpret_cast<const float4*>(&Bg[gofs]);
        xv[it] = *reinterpret_cast<const float4*>(&Xg[gofs]);
    }
    const __bf16* st = states + ((((size_t)bb*16 + hh)*64 + cc) << 12);
    const int p0s = tid >> 3, n8s = (tid & 7)*8;
    const bf16x8 sv0 = *reinterpret_cast<const bf16x8*>(&st[p0s*64 + n8s]);
    const bf16x8 sv1 = *reinterpret_cast<const bf16x8*>(&st[(p0s + 32)*64 + n8s]);

    // ---- A scan (wave 0), overlapped with loads in flight ----
    if (tid < 64) {
        float v = Ag[(tbase + tid)*16 + hh];
        #pragma unroll
        for (int o = 1; o < 64; o <<= 1) { float u = __shfl_up(v, o, 64); if (tid >= o) v += u; }
        sm.dout[tid] = expf(v);
        sm.din[tid]  = expf(-v);
    }

    // ---- stage to LDS ----
    #pragma unroll
    for (int it = 0; it < 4; ++it) {
        const int flat = tid + 256*it;
        const int l  = flat >> 4;
        const int c4 = (flat & 15)*4;
        *reinterpret_cast<bf16x4*>(&sm.Ct[l][c4]) =
            (bf16x4){(__bf16)cv[it].x, (__bf16)cv[it].y, (__bf16)cv[it].z, (__bf16)cv[it].w};
        *reinterpret_cast<bf16x4*>(&sm.BM[l][c4]) =
            (bf16x4){(__bf16)bv[it].x, (__bf16)bv[it].y, (__bf16)bv[it].z, (__bf16)bv[it].w};
        sm.Xt[c4+0][l] = (__bf16)xv[it].x;
        sm.Xt[c4+1][l] = (__bf16)xv[it].y;
        sm.Xt[c4+2][l] = (__bf16)xv[it].z;
        sm.Xt[c4+3][l] = (__bf16)xv[it].w;
    }
    *reinterpret_cast<bf16x8*>(&sm.Sp[p0s][n8s]) = sv0;
    *reinterpret_cast<bf16x8*>(&sm.Sp[p0s + 32][n8s]) = sv1;
    __syncthreads();   // S1

    const int lane = tid & 63;
    const int wm = ((tid >> 7) & 1) * 32;
    const int wn = ((tid >> 6) & 1) * 32;
    const int fr = lane & 15, fg = lane >> 4;

    // ---- phase 1: G = C B^T  and  ao = C @ Sp^T ----
    f32x4 g[2][2] = {}, ao[2][2] = {};
    #pragma unroll
    for (int ks = 0; ks < 2; ++ks) {
        const int k0 = ks*32 + fg*8;
        const bf16x8 c0 = *reinterpret_cast<const bf16x8*>(&sm.Ct[wm      + fr][k0]);
        const bf16x8 c1 = *reinterpret_cast<const bf16x8*>(&sm.Ct[wm + 16 + fr][k0]);
        const bf16x8 b0 = *reinterpret_cast<const bf16x8*>(&sm.BM[wn      + fr][k0]);
        const bf16x8 b1 = *reinterpret_cast<const bf16x8*>(&sm.BM[wn + 16 + fr][k0]);
        g[0][0] = mfma16(c0, b0, g[0][0]);
        g[0][1] = mfma16(c0, b1, g[0][1]);
        g[1][0] = mfma16(c1, b0, g[1][0]);
        g[1][1] = mfma16(c1, b1, g[1][1]);
        const bf16x8 s0 = *reinterpret_cast<const bf16x8*>(&sm.Sp[wn      + fr][k0]);
        const bf16x8 s1 = *reinterpret_cast<const bf16x8*>(&sm.Sp[wn + 16 + fr][k0]);
        ao[0][0] = mfma16(c0, s0, ao[0][0]);
        ao[0][1] = mfma16(c0, s1, ao[0][1]);
        ao[1][0] = mfma16(c1, s0, ao[1][0]);
        ao[1][1] = mfma16(c1, s1, ao[1][1]);
    }
    __syncthreads();   // S2: all BM(B) reads done

    // ---- M (masked decay) overlaid onto BM ----
    #pragma unroll
    for (int mt = 0; mt < 2; ++mt)
        #pragma unroll
        for (int nt = 0; nt < 2; ++nt) {
            const int j = wn + 16*nt + fr;
            const float dj = sm.din[j];
            #pragma unroll
            for (int r = 0; r < 4; ++r) {
                const int i = wm + 16*mt + fg*4 + r;
                const float val = (i >= j) ? g[mt][nt][r] * sm.dout[i] * dj : 0.0f;
                sm.BM[i][j] = (__bf16)val;
            }
        }
    __syncthreads();   // S3: M fully written

    // ---- phase 2: ad = M @ X ----
    f32x4 ad[2][2] = {};
    #pragma unroll
    for (int ks = 0; ks < 2; ++ks) {
        const int k0 = ks*32 + fg*8;
        const bf16x8 m0 = *reinterpret_cast<const bf16x8*>(&sm.BM[wm      + fr][k0]);
        const bf16x8 m1 = *reinterpret_cast<const bf16x8*>(&sm.BM[wm + 16 + fr][k0]);
        const bf16x8 x0 = *reinterpret_cast<const bf16x8*>(&sm.Xt[wn      + fr][k0]);
        const bf16x8 x1 = *reinterpret_cast<const bf16x8*>(&sm.Xt[wn + 16 + fr][k0]);
        ad[0][0] = mfma16(m0, x0, ad[0][0]);
        ad[0][1] = mfma16(m0, x1, ad[0][1]);
        ad[1][0] = mfma16(m1, x0, ad[1][0]);
        ad[1][1] = mfma16(m1, x1, ad[1][1]);
    }

    // ---- combine into sY, overlaid on Ct+Sp (17408 B <= 18432 B) ----
    float (*sY)[68] = reinterpret_cast<float(*)[68]>(&sm);
    #pragma unroll
    for (int mt = 0; mt < 2; ++mt)
        #pragma unroll
        for (int nt = 0; nt < 2; ++nt) {
            const int pcol = wn + 16*nt + fr;
            #pragma unroll
            for (int r = 0; r < 4; ++r) {
                const int i = wm + 16*mt + fg*4 + r;
                sY[i][pcol] = ad[mt][nt][r] + sm.dout[i]*ao[mt][nt][r];
            }
        }
    __syncthreads();   // S4

    #pragma unroll
    for (int it = 0; it < 4; ++it) {
        const int flat = tid + 256*it;
        const int row = flat >> 4;
        const int q4  = (flat & 15)*4;
        const float4 v = *reinterpret_cast<const float4*>(&sY[row][q4]);
        *reinterpret_cast<float4*>(&Yg[((tbase + row)*16 + hh)*(size_t)64 + q4]) = v;
    }
}

extern "C" void kernel_launch(void* const* d_in, const int* in_sizes, int n_in,
                              void* d_out, int out_size, void* d_ws, size_t ws_size,
                              hipStream_t stream) {
    const float* X  = (const float*)d_in[0];
    const float* I  = (const float*)d_in[1];
    const float* A  = (const float*)d_in[2];
    const float* Bp = (const float*)d_in[3];
    const float* Cp = (const float*)d_in[4];
    float* Y = (float*)d_out;
    __bf16* states = (__bf16*)d_ws;                                   // 67,108,864 B
    float*  cs63   = (float*)((char*)d_ws + (size_t)67108864);        // 32,768 B

    kA_chunkstate<<<dim3(64,16,8), 256, 0, stream>>>(X, A, Bp, states, cs63);
    kB_scan      <<<dim3(2,16,8),  256, 0, stream>>>(I, states, cs63);
    kC_output    <<<dim3(64,16,8), 256, 0, stream>>>(X, A, Bp, Cp, states, Y);
}